// Round 2
// baseline (884.219 us; speedup 1.0000x reference)
//
#include <hip/hip_runtime.h>
#include <hip/hip_bf16.h>

#define N_NODES 100000
#define N_EDGES 1000000
#define EPS 1e-5f
#define SLOPE 0.1f

typedef __attribute__((ext_vector_type(8))) short short8;
typedef __attribute__((ext_vector_type(4))) float f32x4;

#define MFMA16(a, b, c) __builtin_amdgcn_mfma_f32_16x16x32_bf16(a, b, c, 0, 0, 0)

__device__ __forceinline__ float lrelu(float v) { return v > 0.f ? v : SLOPE * v; }

__device__ __forceinline__ unsigned short f2bf(float f) {
  __hip_bfloat16 h = __float2bfloat16(f);
  return __builtin_bit_cast(unsigned short, h);
}
__device__ __forceinline__ unsigned pk2(float lo, float hi) {
  return (unsigned)f2bf(lo) | ((unsigned)f2bf(hi) << 16);
}
__device__ __forceinline__ float blo(unsigned u) { return __uint_as_float(u << 16); }
__device__ __forceinline__ float bhi(unsigned u) { return __uint_as_float(u & 0xffff0000u); }

__device__ __forceinline__ short8 mk_frag8(const float v[8]) {
  uint4 u;
  u.x = pk2(v[0], v[1]);
  u.y = pk2(v[2], v[3]);
  u.z = pk2(v[4], v[5]);
  u.w = pk2(v[6], v[7]);
  return __builtin_bit_cast(short8, u);
}

// ============================================================================
// Fused node MLP: x_t = (lrelu(x@W1n + b1n))@W2n + b2n, stored bf16 [N,64].
// Both layers operand-swapped: D = W^T (tiles as A) x in^T (B). Per wave-tile
// of 16 nodes. Layer1 out (h^T) redistributes to layer2 B-frags via shfl.
// ============================================================================
__global__ __launch_bounds__(256) void node_mfma(const float* __restrict__ x,
                                                 const float* __restrict__ W1n,
                                                 const float* __restrict__ b1n,
                                                 const float* __restrict__ W2n,
                                                 const float* __restrict__ b2n,
                                                 __hip_bfloat16* __restrict__ xt) {
  const int lane = threadIdx.x & 63;
  const int lo = lane & 15;
  const int G = lane >> 4;
  const int wid = (blockIdx.x * blockDim.x + threadIdx.x) >> 6;
  const int nw = (gridDim.x * blockDim.x) >> 6;

  // A1[t][kt]: W1n^T tile t (hcols t*16+lo), k = kt*32 + G*8 + j
  short8 A1[8][2];
#pragma unroll
  for (int t = 0; t < 8; ++t)
#pragma unroll
    for (int kt = 0; kt < 2; ++kt) {
      float v[8];
#pragma unroll
      for (int j = 0; j < 8; ++j) v[j] = W1n[(kt * 32 + G * 8 + j) * 128 + t * 16 + lo];
      A1[t][kt] = mk_frag8(v);
    }
  // A2[ct][kt]: W2n^T tile ct (out-dims ct*16+lo), k = kt*32 + G*8 + j
  short8 A2[4][4];
#pragma unroll
  for (int ct = 0; ct < 4; ++ct)
#pragma unroll
    for (int kt = 0; kt < 4; ++kt) {
      float v[8];
#pragma unroll
      for (int j = 0; j < 8; ++j) v[j] = W2n[(kt * 32 + G * 8 + j) * 64 + ct * 16 + lo];
      A2[ct][kt] = mk_frag8(v);
    }
  const f32x4 zero = {0.f, 0.f, 0.f, 0.f};

  for (int tile = wid; tile < N_NODES / 16; tile += nw) {
    const int n0 = tile * 16;
    // B1[kt]: x^T frag — lane holds x[node n0+lo][kt*32 + G*8 + j]
    short8 B1[2];
#pragma unroll
    for (int kt = 0; kt < 2; ++kt) {
      const float* p = &x[(size_t)(n0 + lo) * 64 + kt * 32 + G * 8];
      float4 q0 = *(const float4*)p;
      float4 q1 = *(const float4*)(p + 4);
      float v[8] = {q0.x, q0.y, q0.z, q0.w, q1.x, q1.y, q1.z, q1.w};
      B1[kt] = mk_frag8(v);
    }
    // Layer 1: h^T tiles -> lrelu(+bias) -> packed bf16 pairs
    // P[t][p] on lane l = pack(h[node lo][t*16+G*4+2p], h[..][t*16+G*4+2p+1])
    unsigned P[8][2];
#pragma unroll
    for (int t = 0; t < 8; ++t) {
      f32x4 d = MFMA16(A1[t][0], B1[0], zero);
      d = MFMA16(A1[t][1], B1[1], d);
      const float4 bv = *(const float4*)&b1n[t * 16 + G * 4];
      P[t][0] = pk2(lrelu(d[0] + bv.x), lrelu(d[1] + bv.y));
      P[t][1] = pk2(lrelu(d[2] + bv.z), lrelu(d[3] + bv.w));
    }
    // Layer 2: B2 slot j needs h[node lo][k = kt*32 + G*8 + j]
    //   tile t = kt*2 + (G>>1); src group s = 2*(G&1) + (j>>2); reg = j&3
    f32x4 D2[4] = {zero, zero, zero, zero};
#pragma unroll
    for (int kt = 0; kt < 4; ++kt) {
      unsigned u[4];
#pragma unroll
      for (int i = 0; i < 4; ++i) {
        const int srcidx = lo + 16 * (2 * (G & 1) + (i >> 1));
        unsigned r0 = (unsigned)__shfl((int)P[kt * 2][i & 1], srcidx);
        unsigned r1 = (unsigned)__shfl((int)P[kt * 2 + 1][i & 1], srcidx);
        u[i] = (lane >= 32) ? r1 : r0;
      }
      uint4 uu;
      uu.x = u[0]; uu.y = u[1]; uu.z = u[2]; uu.w = u[3];
      short8 B2 = __builtin_bit_cast(short8, uu);
#pragma unroll
      for (int ct = 0; ct < 4; ++ct) D2[ct] = MFMA16(A2[ct][kt], B2, D2[ct]);
    }
    // Store x_t bf16: lane owns node lo, dims ct*16 + G*4 + {0..3}
    unsigned short* row = (unsigned short*)xt + (size_t)(n0 + lo) * 64;
#pragma unroll
    for (int ct = 0; ct < 4; ++ct) {
      const float4 bv = *(const float4*)&b2n[ct * 16 + G * 4];
      uint2 s;
      s.x = pk2(D2[ct][0] + bv.x, D2[ct][1] + bv.y);
      s.y = pk2(D2[ct][2] + bv.z, D2[ct][3] + bv.w);
      *(uint2*)(row + ct * 16 + G * 4) = s;
    }
  }
}

// ============================================================================
// Fused edge pipeline: e_t = MLP(edge_attr) via MFMA (both layers swapped),
// then msg = x_t[src] * e_t * dp_scale, atomic scatter into agg (= d_out).
// ============================================================================
__global__ __launch_bounds__(256) void edge_mfma(const float* __restrict__ ea,
                                                 const int* __restrict__ ei,
                                                 const float* __restrict__ W1e,
                                                 const float* __restrict__ b1e,
                                                 const float* __restrict__ W2e,
                                                 const float* __restrict__ b2e,
                                                 const __hip_bfloat16* __restrict__ xt,
                                                 const float* __restrict__ dp,
                                                 float* __restrict__ agg) {
  const int lane = threadIdx.x & 63;
  const int lo = lane & 15;
  const int G = lane >> 4;
  const int wid = (blockIdx.x * blockDim.x + threadIdx.x) >> 6;
  const int nw = (gridDim.x * blockDim.x) >> 6;
  const float scale = dp[0];

  short8 A1[4];  // W1e^T tiles, K=32 (single k-tile)
#pragma unroll
  for (int t = 0; t < 4; ++t) {
    float v[8];
#pragma unroll
    for (int j = 0; j < 8; ++j) v[j] = W1e[(G * 8 + j) * 64 + t * 16 + lo];
    A1[t] = mk_frag8(v);
  }
  short8 A2[4][2];  // W2e^T tiles, K=64 (2 k-tiles)
#pragma unroll
  for (int t = 0; t < 4; ++t)
#pragma unroll
    for (int kt = 0; kt < 2; ++kt) {
      float v[8];
#pragma unroll
      for (int j = 0; j < 8; ++j) v[j] = W2e[(kt * 32 + G * 8 + j) * 64 + t * 16 + lo];
      A2[t][kt] = mk_frag8(v);
    }
  // biases as C-init (row of D = output dim = t*16 + G*4 + r)
  f32x4 Cb1[4], Cb2[4];
#pragma unroll
  for (int t = 0; t < 4; ++t)
#pragma unroll
    for (int r = 0; r < 4; ++r) {
      Cb1[t][r] = b1e[t * 16 + G * 4 + r];
      Cb2[t][r] = b2e[t * 16 + G * 4 + r];
    }

  for (int tile = wid; tile < N_EDGES / 16; tile += nw) {
    const int e0 = tile * 16;
    // B1: lane holds ea[edge e0+lo][G*8 + j]
    const float* p = &ea[(size_t)(e0 + lo) * 32 + G * 8];
    float4 q0 = *(const float4*)p;
    float4 q1 = *(const float4*)(p + 4);
    float v[8] = {q0.x, q0.y, q0.z, q0.w, q1.x, q1.y, q1.z, q1.w};
    short8 B1 = mk_frag8(v);

    unsigned P[4][2];
#pragma unroll
    for (int t = 0; t < 4; ++t) {
      f32x4 d = MFMA16(A1[t], B1, Cb1[t]);
      P[t][0] = pk2(lrelu(d[0]), lrelu(d[1]));
      P[t][1] = pk2(lrelu(d[2]), lrelu(d[3]));
    }
    short8 B2f[2];
#pragma unroll
    for (int kt = 0; kt < 2; ++kt) {
      unsigned u[4];
#pragma unroll
      for (int i = 0; i < 4; ++i) {
        const int srcidx = lo + 16 * (2 * (G & 1) + (i >> 1));
        unsigned r0 = (unsigned)__shfl((int)P[kt * 2][i & 1], srcidx);
        unsigned r1 = (unsigned)__shfl((int)P[kt * 2 + 1][i & 1], srcidx);
        u[i] = (lane >= 32) ? r1 : r0;
      }
      uint4 uu;
      uu.x = u[0]; uu.y = u[1]; uu.z = u[2]; uu.w = u[3];
      B2f[kt] = __builtin_bit_cast(short8, uu);
    }
    f32x4 D2[4];  // e_t^T: lane holds e_t[edge lo][t*16 + G*4 + r]
#pragma unroll
    for (int t = 0; t < 4; ++t) {
      f32x4 d = MFMA16(A2[t][0], B2f[0], Cb2[t]);
      D2[t] = MFMA16(A2[t][1], B2f[1], d);
    }
    // Apply: gather x_t[src], multiply, scatter-add to agg[dst]
    const int e = e0 + lo;
    const int src = ei[e];
    const int dst = ei[N_EDGES + e];
    const unsigned short* xrow = (const unsigned short*)xt + (size_t)src * 64;
    float* arow = agg + (size_t)dst * 64;
#pragma unroll
    for (int t = 0; t < 4; ++t) {
      uint2 g = *(const uint2*)(xrow + t * 16 + G * 4);
      unsafeAtomicAdd(arow + t * 16 + G * 4 + 0, blo(g.x) * D2[t][0] * scale);
      unsafeAtomicAdd(arow + t * 16 + G * 4 + 1, bhi(g.x) * D2[t][1] * scale);
      unsafeAtomicAdd(arow + t * 16 + G * 4 + 2, blo(g.y) * D2[t][2] * scale);
      unsafeAtomicAdd(arow + t * 16 + G * 4 + 3, bhi(g.y) * D2[t][3] * scale);
    }
  }
}

// ---- residual + LayerNorm, in place on d_out (which holds the aggregate)
__global__ __launch_bounds__(256) void finalize(const float* __restrict__ x,
                                                const float* __restrict__ res_w,
                                                const float* __restrict__ gamma,
                                                const float* __restrict__ beta,
                                                float* __restrict__ out) {
  const int lane = threadIdx.x & 63;
  const int wid = (blockIdx.x * blockDim.x + threadIdx.x) >> 6;
  const int nw = (gridDim.x * blockDim.x) >> 6;
  const float rw = res_w[0];
  const float g = gamma[lane], bb = beta[lane];
  for (int n = wid; n < N_NODES; n += nw) {
    float v = fmaf(out[(size_t)n * 64 + lane], rw, x[(size_t)n * 64 + lane]);
    float s = v;
#pragma unroll
    for (int off = 1; off < 64; off <<= 1) s += __shfl_xor(s, off);
    const float mu = s * (1.f / 64.f);
    const float d = v - mu;
    float s2 = d * d;
#pragma unroll
    for (int off = 1; off < 64; off <<= 1) s2 += __shfl_xor(s2, off);
    out[(size_t)n * 64 + lane] = fmaf(d * rsqrtf(s2 * (1.f / 64.f) + EPS), g, bb);
  }
}

extern "C" void kernel_launch(void* const* d_in, const int* in_sizes, int n_in,
                              void* d_out, int out_size, void* d_ws, size_t ws_size,
                              hipStream_t stream) {
  const float* x = (const float*)d_in[0];
  const float* edge_attr = (const float*)d_in[1];
  const float* W1n = (const float*)d_in[2];
  const float* b1n = (const float*)d_in[3];
  const float* W2n = (const float*)d_in[4];
  const float* b2n = (const float*)d_in[5];
  const float* W1e = (const float*)d_in[6];
  const float* b1e = (const float*)d_in[7];
  const float* W2e = (const float*)d_in[8];
  const float* b2e = (const float*)d_in[9];
  const float* res_w = (const float*)d_in[10];
  const float* dp_scale = (const float*)d_in[11];
  const float* gamma = (const float*)d_in[12];
  const float* beta = (const float*)d_in[13];
  const int* edge_index = (const int*)d_in[14];
  float* out = (float*)d_out;

  __hip_bfloat16* xt = (__hip_bfloat16*)d_ws;  // N_NODES * 64 bf16 = 12.8 MB

  hipMemsetAsync(d_out, 0, (size_t)out_size * sizeof(float), stream);
  node_mfma<<<512, 256, 0, stream>>>(x, W1n, b1n, W2n, b2n, xt);
  edge_mfma<<<768, 256, 0, stream>>>(edge_attr, edge_index, W1e, b1e, W2e, b2e,
                                     xt, dp_scale, out);
  finalize<<<1024, 256, 0, stream>>>(x, res_w, gamma, beta, out);
}

// Round 3
// 266.587 us; speedup vs baseline: 3.3168x; 3.3168x over previous
//
#include <hip/hip_runtime.h>
#include <hip/hip_bf16.h>

#define N_NODES 100000
#define N_EDGES 1000000
#define EPS 1e-5f
#define SLOPE 0.1f

typedef __attribute__((ext_vector_type(8))) short short8;
typedef __attribute__((ext_vector_type(4))) float f32x4;

#define MFMA16(a, b, c) __builtin_amdgcn_mfma_f32_16x16x32_bf16(a, b, c, 0, 0, 0)

__device__ __forceinline__ float lrelu(float v) { return v > 0.f ? v : SLOPE * v; }

__device__ __forceinline__ unsigned short f2bf(float f) {
  __hip_bfloat16 h = __float2bfloat16(f);
  return __builtin_bit_cast(unsigned short, h);
}
__device__ __forceinline__ unsigned pk2(float lo, float hi) {
  return (unsigned)f2bf(lo) | ((unsigned)f2bf(hi) << 16);
}

__device__ __forceinline__ short8 mk_frag8(const float v[8]) {
  uint4 u;
  u.x = pk2(v[0], v[1]);
  u.y = pk2(v[2], v[3]);
  u.z = pk2(v[4], v[5]);
  u.w = pk2(v[6], v[7]);
  return __builtin_bit_cast(short8, u);
}

// ============================================================================
// Fused node MLP: x_t = (lrelu(x@W1n + b1n))@W2n + b2n, stored bf16 [N,64].
// Both layers operand-swapped: D = W^T (tiles as A) x in^T (B). Per wave-tile
// of 16 nodes. Layer1 out (h^T) redistributes to layer2 B-frags via shfl.
// ============================================================================
__global__ __launch_bounds__(256) void node_mfma(const float* __restrict__ x,
                                                 const float* __restrict__ W1n,
                                                 const float* __restrict__ b1n,
                                                 const float* __restrict__ W2n,
                                                 const float* __restrict__ b2n,
                                                 __hip_bfloat16* __restrict__ xt) {
  const int lane = threadIdx.x & 63;
  const int lo = lane & 15;
  const int G = lane >> 4;
  const int wid = (blockIdx.x * blockDim.x + threadIdx.x) >> 6;
  const int nw = (gridDim.x * blockDim.x) >> 6;

  short8 A1[8][2];
#pragma unroll
  for (int t = 0; t < 8; ++t)
#pragma unroll
    for (int kt = 0; kt < 2; ++kt) {
      float v[8];
#pragma unroll
      for (int j = 0; j < 8; ++j) v[j] = W1n[(kt * 32 + G * 8 + j) * 128 + t * 16 + lo];
      A1[t][kt] = mk_frag8(v);
    }
  short8 A2[4][4];
#pragma unroll
  for (int ct = 0; ct < 4; ++ct)
#pragma unroll
    for (int kt = 0; kt < 4; ++kt) {
      float v[8];
#pragma unroll
      for (int j = 0; j < 8; ++j) v[j] = W2n[(kt * 32 + G * 8 + j) * 64 + ct * 16 + lo];
      A2[ct][kt] = mk_frag8(v);
    }
  const f32x4 zero = {0.f, 0.f, 0.f, 0.f};

  for (int tile = wid; tile < N_NODES / 16; tile += nw) {
    const int n0 = tile * 16;
    short8 B1[2];
#pragma unroll
    for (int kt = 0; kt < 2; ++kt) {
      const float* p = &x[(size_t)(n0 + lo) * 64 + kt * 32 + G * 8];
      float4 q0 = *(const float4*)p;
      float4 q1 = *(const float4*)(p + 4);
      float v[8] = {q0.x, q0.y, q0.z, q0.w, q1.x, q1.y, q1.z, q1.w};
      B1[kt] = mk_frag8(v);
    }
    unsigned P[8][2];
#pragma unroll
    for (int t = 0; t < 8; ++t) {
      f32x4 d = MFMA16(A1[t][0], B1[0], zero);
      d = MFMA16(A1[t][1], B1[1], d);
      const float4 bv = *(const float4*)&b1n[t * 16 + G * 4];
      P[t][0] = pk2(lrelu(d[0] + bv.x), lrelu(d[1] + bv.y));
      P[t][1] = pk2(lrelu(d[2] + bv.z), lrelu(d[3] + bv.w));
    }
    f32x4 D2[4] = {zero, zero, zero, zero};
#pragma unroll
    for (int kt = 0; kt < 4; ++kt) {
      unsigned u[4];
#pragma unroll
      for (int i = 0; i < 4; ++i) {
        const int srcidx = lo + 16 * (2 * (G & 1) + (i >> 1));
        unsigned r0 = (unsigned)__shfl((int)P[kt * 2][i & 1], srcidx);
        unsigned r1 = (unsigned)__shfl((int)P[kt * 2 + 1][i & 1], srcidx);
        u[i] = (lane >= 32) ? r1 : r0;
      }
      uint4 uu;
      uu.x = u[0]; uu.y = u[1]; uu.z = u[2]; uu.w = u[3];
      short8 B2 = __builtin_bit_cast(short8, uu);
#pragma unroll
      for (int ct = 0; ct < 4; ++ct) D2[ct] = MFMA16(A2[ct][kt], B2, D2[ct]);
    }
    unsigned short* row = (unsigned short*)xt + (size_t)(n0 + lo) * 64;
#pragma unroll
    for (int ct = 0; ct < 4; ++ct) {
      const float4 bv = *(const float4*)&b2n[ct * 16 + G * 4];
      uint2 s;
      s.x = pk2(D2[ct][0] + bv.x, D2[ct][1] + bv.y);
      s.y = pk2(D2[ct][2] + bv.z, D2[ct][3] + bv.w);
      *(uint2*)(row + ct * 16 + G * 4) = s;
    }
  }
}

// ============================================================================
// Fused edge pipeline: e_t = MLP(edge_attr) via MFMA (16 edges per wave),
// transpose msgs through per-wave LDS, then per-edge row-contiguous
// gather+multiply+atomic scatter (whole wave on one edge = 256B atomic).
// ============================================================================
__global__ __launch_bounds__(256) void edge_mfma(const float* __restrict__ ea,
                                                 const int* __restrict__ ei,
                                                 const float* __restrict__ W1e,
                                                 const float* __restrict__ b1e,
                                                 const float* __restrict__ W2e,
                                                 const float* __restrict__ b2e,
                                                 const __hip_bfloat16* __restrict__ xt,
                                                 const float* __restrict__ dp,
                                                 float* __restrict__ agg) {
  const int lane = threadIdx.x & 63;
  const int lo = lane & 15;
  const int G = lane >> 4;
  const int w = threadIdx.x >> 6;  // wave within block
  const int wid = (blockIdx.x * blockDim.x + threadIdx.x) >> 6;
  const int nw = (gridDim.x * blockDim.x) >> 6;
  const float scale = dp[0];

  __shared__ float msg_lds[4][16 * 68];  // per-wave [16 edges][64+4 pad] f32
  float* ml = &msg_lds[w][0];

  short8 A1[4];
#pragma unroll
  for (int t = 0; t < 4; ++t) {
    float v[8];
#pragma unroll
    for (int j = 0; j < 8; ++j) v[j] = W1e[(G * 8 + j) * 64 + t * 16 + lo];
    A1[t] = mk_frag8(v);
  }
  short8 A2[4][2];
#pragma unroll
  for (int t = 0; t < 4; ++t)
#pragma unroll
    for (int kt = 0; kt < 2; ++kt) {
      float v[8];
#pragma unroll
      for (int j = 0; j < 8; ++j) v[j] = W2e[(kt * 32 + G * 8 + j) * 64 + t * 16 + lo];
      A2[t][kt] = mk_frag8(v);
    }
  f32x4 Cb1[4], Cb2[4];
#pragma unroll
  for (int t = 0; t < 4; ++t)
#pragma unroll
    for (int r = 0; r < 4; ++r) {
      Cb1[t][r] = b1e[t * 16 + G * 4 + r];
      Cb2[t][r] = b2e[t * 16 + G * 4 + r];
    }

  for (int tile = wid; tile < N_EDGES / 16; tile += nw) {
    const int e0 = tile * 16;
    // edge indices for this tile (lane lo's edge; replicated across G)
    const int srcv = ei[e0 + lo];
    const int dstv = ei[N_EDGES + e0 + lo];
    // B1: lane holds ea[edge e0+lo][G*8 + j]
    const float* p = &ea[(size_t)(e0 + lo) * 32 + G * 8];
    float4 q0 = *(const float4*)p;
    float4 q1 = *(const float4*)(p + 4);
    float v[8] = {q0.x, q0.y, q0.z, q0.w, q1.x, q1.y, q1.z, q1.w};
    short8 B1 = mk_frag8(v);

    unsigned P[4][2];
#pragma unroll
    for (int t = 0; t < 4; ++t) {
      f32x4 d = MFMA16(A1[t], B1, Cb1[t]);
      P[t][0] = pk2(lrelu(d[0]), lrelu(d[1]));
      P[t][1] = pk2(lrelu(d[2]), lrelu(d[3]));
    }
    short8 B2f[2];
#pragma unroll
    for (int kt = 0; kt < 2; ++kt) {
      unsigned u[4];
#pragma unroll
      for (int i = 0; i < 4; ++i) {
        const int srcidx = lo + 16 * (2 * (G & 1) + (i >> 1));
        unsigned r0 = (unsigned)__shfl((int)P[kt * 2][i & 1], srcidx);
        unsigned r1 = (unsigned)__shfl((int)P[kt * 2 + 1][i & 1], srcidx);
        u[i] = (lane >= 32) ? r1 : r0;
      }
      uint4 uu;
      uu.x = u[0]; uu.y = u[1]; uu.z = u[2]; uu.w = u[3];
      B2f[kt] = __builtin_bit_cast(short8, uu);
    }
    // e_t^T with dp_scale folded: lane holds e_t[edge lo][t*16+G*4+r]*scale
    // -> write to per-wave LDS, transposed out via per-edge reads below
#pragma unroll
    for (int t = 0; t < 4; ++t) {
      f32x4 d = MFMA16(A2[t][0], B2f[0], Cb2[t]);
      d = MFMA16(A2[t][1], B2f[1], d);
      f32x4 sv;
#pragma unroll
      for (int r = 0; r < 4; ++r) sv[r] = d[r] * scale;
      *(f32x4*)&ml[lo * 68 + t * 16 + G * 4] = sv;
    }
    // per-edge: whole wave handles edge e's 64 dims -> contiguous 256B atomic
#pragma unroll 4
    for (int e = 0; e < 16; ++e) {
      const int se = __builtin_amdgcn_readlane(srcv, e);
      const int de = __builtin_amdgcn_readlane(dstv, e);
      const float m = ml[e * 68 + lane];
      const unsigned short xb = ((const unsigned short*)xt)[(size_t)se * 64 + lane];
      const float xs = __uint_as_float(((unsigned)xb) << 16);
      unsafeAtomicAdd(agg + (size_t)de * 64 + lane, xs * m);
    }
  }
}

// ---- residual + LayerNorm, in place on d_out (which holds the aggregate)
__global__ __launch_bounds__(256) void finalize(const float* __restrict__ x,
                                                const float* __restrict__ res_w,
                                                const float* __restrict__ gamma,
                                                const float* __restrict__ beta,
                                                float* __restrict__ out) {
  const int lane = threadIdx.x & 63;
  const int wid = (blockIdx.x * blockDim.x + threadIdx.x) >> 6;
  const int nw = (gridDim.x * blockDim.x) >> 6;
  const float rw = res_w[0];
  const float g = gamma[lane], bb = beta[lane];
  for (int n = wid; n < N_NODES; n += nw) {
    float v = fmaf(out[(size_t)n * 64 + lane], rw, x[(size_t)n * 64 + lane]);
    float s = v;
#pragma unroll
    for (int off = 1; off < 64; off <<= 1) s += __shfl_xor(s, off);
    const float mu = s * (1.f / 64.f);
    const float d = v - mu;
    float s2 = d * d;
#pragma unroll
    for (int off = 1; off < 64; off <<= 1) s2 += __shfl_xor(s2, off);
    out[(size_t)n * 64 + lane] = fmaf(d * rsqrtf(s2 * (1.f / 64.f) + EPS), g, bb);
  }
}

extern "C" void kernel_launch(void* const* d_in, const int* in_sizes, int n_in,
                              void* d_out, int out_size, void* d_ws, size_t ws_size,
                              hipStream_t stream) {
  const float* x = (const float*)d_in[0];
  const float* edge_attr = (const float*)d_in[1];
  const float* W1n = (const float*)d_in[2];
  const float* b1n = (const float*)d_in[3];
  const float* W2n = (const float*)d_in[4];
  const float* b2n = (const float*)d_in[5];
  const float* W1e = (const float*)d_in[6];
  const float* b1e = (const float*)d_in[7];
  const float* W2e = (const float*)d_in[8];
  const float* b2e = (const float*)d_in[9];
  const float* res_w = (const float*)d_in[10];
  const float* dp_scale = (const float*)d_in[11];
  const float* gamma = (const float*)d_in[12];
  const float* beta = (const float*)d_in[13];
  const int* edge_index = (const int*)d_in[14];
  float* out = (float*)d_out;

  __hip_bfloat16* xt = (__hip_bfloat16*)d_ws;  // N_NODES * 64 bf16 = 12.8 MB

  hipMemsetAsync(d_out, 0, (size_t)out_size * sizeof(float), stream);
  node_mfma<<<512, 256, 0, stream>>>(x, W1n, b1n, W2n, b2n, xt);
  edge_mfma<<<1024, 256, 0, stream>>>(edge_attr, edge_index, W1e, b1e, W2e, b2e,
                                      xt, dp_scale, out);
  finalize<<<1024, 256, 0, stream>>>(x, res_w, gamma, beta, out);
}